// Round 1
// baseline (86.984 us; speedup 1.0000x reference)
//
#include <hip/hip_runtime.h>

// Problem constants (shapes are static per setup_inputs):
//   audio:  [2, 1500, 1024] f32   (unused -- see analytic identity)
//   ctx:    [2, 4096, 1024] f32
//   amask:  [2, 1500] i32         (unused)
//   cmask:  [2, 4096] i32
//   window_size = 4
// Outputs (concatenated flat in d_out, f32):
//   pooled:    [2, 1024, 1024]  = 0.25 * sum over each window of 4 ctx rows
//   pool_mask: [2, 1024]        = (window-sum of cmask) > 0 ? 1 : 0
//
// Identity: softmax over q then sum over q == 1 exactly -> per-(b,n,k) weight
// is constant -> window softmax of a constant is uniform 0.25. The QK^T,
// both softmaxes, audio tensor and audio mask drop out of the math.

#define BSZ     2
#define CTXLEN  4096
#define HID     1024
#define WIN     4
#define GROUPS  (CTXLEN / WIN)          // 1024
#define POOL_ELEMS (BSZ * GROUPS * HID) // 2097152 f32
#define MASK_ELEMS (BSZ * GROUPS)       // 2048
#define TOTAL4  (POOL_ELEMS / 4)        // 524288 float4 outputs

__global__ __launch_bounds__(256) void sap2_pool_kernel(
        const float* __restrict__ ctx,
        const int*   __restrict__ cmask,
        float*       __restrict__ out) {
    const int stride = gridDim.x * blockDim.x;
    int tid = blockIdx.x * blockDim.x + threadIdx.x;

    const float4* c4 = reinterpret_cast<const float4*>(ctx);
    float4*       o4 = reinterpret_cast<float4*>(out);

    // pooled: i indexes [b*GROUPS+g][c4] with c4 in [0,256)
    for (int i = tid; i < TOTAL4; i += stride) {
        const int c  = i & (HID / 4 - 1);   // 0..255
        const int bg = i >> 8;              // b*GROUPS + g
        // ctx row s = 4*g + w in batch b -> float4 index (bg*4 + w)*256 + c
        const int base = (bg << 2) * (HID / 4) + c;
        const float4 a = c4[base];
        const float4 b = c4[base + (HID / 4)];
        const float4 cc = c4[base + 2 * (HID / 4)];
        const float4 d = c4[base + 3 * (HID / 4)];
        float4 r;
        r.x = 0.25f * ((a.x + b.x) + (cc.x + d.x));
        r.y = 0.25f * ((a.y + b.y) + (cc.y + d.y));
        r.z = 0.25f * ((a.z + b.z) + (cc.z + d.z));
        r.w = 0.25f * ((a.w + b.w) + (cc.w + d.w));
        o4[i] = r;
    }

    // pool_mask: one int4 (= one window) per output
    const int4* m4 = reinterpret_cast<const int4*>(cmask);
    for (int i = tid; i < MASK_ELEMS; i += stride) {
        const int4 m = m4[i];
        const int s = (m.x + m.y) + (m.z + m.w);
        out[POOL_ELEMS + i] = (s > 0) ? 1.0f : 0.0f;
    }
}

extern "C" void kernel_launch(void* const* d_in, const int* in_sizes, int n_in,
                              void* d_out, int out_size, void* d_ws, size_t ws_size,
                              hipStream_t stream) {
    (void)in_sizes; (void)n_in; (void)d_ws; (void)ws_size; (void)out_size;
    const float* ctx   = (const float*)d_in[1];
    const int*   cmask = (const int*)d_in[3];
    float*       out   = (float*)d_out;

    // 2048 blocks x 256 threads = 524288 threads -> exactly one float4 each.
    sap2_pool_kernel<<<2048, 256, 0, stream>>>(ctx, cmask, out);
}

// Round 7
// 85.592 us; speedup vs baseline: 1.0163x; 1.0163x over previous
//
#include <hip/hip_runtime.h>

// Problem constants (static shapes):
//   ctx:    [2, 4096, 1024] f32  (d_in[1])
//   cmask:  [2, 4096] i32        (d_in[3])
//   window_size = 4
// Outputs (concat flat, f32): pooled [2,1024,1024], pool_mask [2,1024]
//
// Analytic identity (see R0): softmax over q summed over q == 1 ->
// per-(b,n,k) weight constant -> window softmax uniform 0.25 ->
// pooled = 0.25 * window-sum of ctx rows; mask = window-sum(cmask) > 0.
// QK^T, both softmaxes, audio and audio-mask drop out exactly.
// Traffic floor: read 33.6 MB ctx + 32 KB mask, write 8.4 MB + 8 KB.
// Verified passing R1 with absmax 7.8e-3.
//
// R5 fix: __builtin_nontemporal_store rejects HIP_vector_type<float,4>;
// use a native clang ext_vector_type instead (accepted by the builtin).

typedef float f32x4 __attribute__((ext_vector_type(4)));

#define BSZ     2
#define CTXLEN  4096
#define HID     1024
#define WIN     4
#define GROUPS  (CTXLEN / WIN)          // 1024
#define POOL_ELEMS (BSZ * GROUPS * HID) // 2097152 f32
#define MASK_ELEMS (BSZ * GROUPS)       // 2048
#define TOTAL4  (POOL_ELEMS / 4)        // 524288 f32x4 outputs
#define H4      (HID / 4)               // 256

__global__ __launch_bounds__(256) void sap2_pool_kernel(
        const float* __restrict__ ctx,
        const int*   __restrict__ cmask,
        float*       __restrict__ out) {
    const int tid = blockIdx.x * 256 + threadIdx.x;   // exactly TOTAL4 threads

    const f32x4* c4 = reinterpret_cast<const f32x4*>(ctx);
    f32x4*       o4 = reinterpret_cast<f32x4*>(out);

    // pooled: tid -> [bg][c] with c in [0,256). Wave reads 1 KB contiguous
    // per load instruction (64 lanes x 16 B), 4 loads at 4 KB row stride.
    const int c    = tid & (H4 - 1);
    const int bg   = tid >> 8;
    const int base = (bg << 2) * H4 + c;
    const f32x4 a = c4[base];
    const f32x4 b = c4[base + H4];
    const f32x4 d = c4[base + 2 * H4];
    const f32x4 e = c4[base + 3 * H4];
    const f32x4 r = 0.25f * ((a + b) + (d + e));
    __builtin_nontemporal_store(r, &o4[tid]);

    // pool_mask: first 2048 threads, one int4 window each.
    if (tid < MASK_ELEMS) {
        const int4 m = reinterpret_cast<const int4*>(cmask)[tid];
        const float v = ((m.x + m.y) + (m.z + m.w)) > 0 ? 1.0f : 0.0f;
        __builtin_nontemporal_store(v, &out[POOL_ELEMS + tid]);
    }
}

extern "C" void kernel_launch(void* const* d_in, const int* in_sizes, int n_in,
                              void* d_out, int out_size, void* d_ws, size_t ws_size,
                              hipStream_t stream) {
    (void)in_sizes; (void)n_in; (void)d_ws; (void)ws_size; (void)out_size;
    const float* ctx   = (const float*)d_in[1];
    const int*   cmask = (const int*)d_in[3];
    float*       out   = (float*)d_out;

    sap2_pool_kernel<<<TOTAL4 / 256, 256, 0, stream>>>(ctx, cmask, out);
}